// Round 2
// baseline (1520.848 us; speedup 1.0000x reference)
//
#include <hip/hip_runtime.h>
#include <hip/hip_bf16.h>

// Problem constants
#define NB   32      // batch (processed in 2 chunks of 16)
#define NBC  16      // batches per chunk
#define HC   30      // conv out H
#define WC   30      // conv out W (padded to 32 in votes slab)
#define ICAP 8       // input capsules (= conv out D)
#define OCAP 16      // output capsules
#define NATM 16      // atoms
#define NCO  256     // OCAP*NATM
// votes workspace layout: slab per (b,h): [i(8)][o(16)][a(16)][w(32 padded)] fp32
// slab elems = 8*256*32 = 65536 ; chunk total = 16*30*65536*4B = 125,829,120 bytes
#define SLAB 65536

// ---------------------------------------------------------------------------
// Kernel 1: conv -> votes (fp32 compute, fp32 store)
// conv[b,co,d,hc,wc] = sum_{kd<16,kh<3,kw<3} xbuf[b, d*16+kd, hc+kh, wc+kw] * W[kd,kh,kw,0,co]
// xbuf = x viewed as [B][128][32][32] (raw reshape of (B,H,W,ic,ia))
// Block: (b, d, hs) computes h = 2*hs, 2*hs+1 ; all 256 co ; wc 0..31 (30 valid)
// ---------------------------------------------------------------------------
__global__ __launch_bounds__(256) void conv_votes_kernel(
    const float* __restrict__ x, const float* __restrict__ Wt,
    float* __restrict__ votes)
{
    const int b  = blockIdx.x;     // 0..15 (chunk-local)
    const int d  = blockIdx.y;     // 8
    const int h0 = blockIdx.z * 2; // 0,2,..,28
    const int t  = threadIdx.x;

    __shared__ union {
        struct {
            float xs[16][4][36];  // [kd][row][col padded] rows h0..h0+3
            float ws[9][256];     // [tap][co] for current kd
        } s;
        float ob[256][33];        // transpose buffer [co][wc]
    } u;

    // stage x rows once: 16*4*36 = 2304 entries
    {
        const float* xb = x + (size_t)b * (128 * 1024) + (size_t)d * (16 * 1024);
        #pragma unroll
        for (int j = 0; j < 9; ++j) {
            int idx = t + j * 256;           // < 2304
            int kd  = idx / 144;
            int rem = idx - kd * 144;
            int r   = rem / 36;
            int z   = rem - r * 36;
            float v = 0.f;
            if (z < 32) v = xb[kd * 1024 + (h0 + r) * 32 + z];
            u.s.xs[kd][r][z] = v;
        }
    }

    const int lane = t & 63;
    const int wg   = t >> 6;        // 0..3 : wc group (same for whole wave)
    const int c0   = lane * 4;      // co quad base
    const int w0   = wg * 8;        // wc base

    float acc[2][8][4];
    #pragma unroll
    for (int hl = 0; hl < 2; ++hl)
        #pragma unroll
        for (int p = 0; p < 8; ++p)
            #pragma unroll
            for (int c = 0; c < 4; ++c) acc[hl][p][c] = 0.f;

    for (int kd = 0; kd < 16; ++kd) {
        __syncthreads();  // previous ws consumers done (also covers xs staging at kd=0)
        #pragma unroll
        for (int j = 0; j < 9; ++j)
            u.s.ws[j][t] = Wt[(kd * 9 + j) * 256 + t];
        __syncthreads();

        #pragma unroll
        for (int kh = 0; kh < 3; ++kh) {
            float xr[2][12];
            #pragma unroll
            for (int hl = 0; hl < 2; ++hl) {
                float4 a4 = *(const float4*)&u.s.xs[kd][kh + hl][w0];
                float4 b4 = *(const float4*)&u.s.xs[kd][kh + hl][w0 + 4];
                float4 c4 = *(const float4*)&u.s.xs[kd][kh + hl][w0 + 8];
                xr[hl][0] = a4.x; xr[hl][1] = a4.y; xr[hl][2]  = a4.z; xr[hl][3]  = a4.w;
                xr[hl][4] = b4.x; xr[hl][5] = b4.y; xr[hl][6]  = b4.z; xr[hl][7]  = b4.w;
                xr[hl][8] = c4.x; xr[hl][9] = c4.y; xr[hl][10] = c4.z; xr[hl][11] = c4.w;
            }
            #pragma unroll
            for (int kw = 0; kw < 3; ++kw) {
                float4 wq = *(const float4*)&u.s.ws[kh * 3 + kw][c0];
                #pragma unroll
                for (int hl = 0; hl < 2; ++hl)
                    #pragma unroll
                    for (int p = 0; p < 8; ++p) {
                        float xv = xr[hl][kw + p];
                        acc[hl][p][0] += xv * wq.x;
                        acc[hl][p][1] += xv * wq.y;
                        acc[hl][p][2] += xv * wq.z;
                        acc[hl][p][3] += xv * wq.w;
                    }
            }
        }
    }

    // epilogue: transpose through LDS, coalesced fp32 store
    #pragma unroll 1
    for (int hl = 0; hl < 2; ++hl) {
        __syncthreads();
        #pragma unroll
        for (int p = 0; p < 8; ++p)
            #pragma unroll
            for (int c = 0; c < 4; ++c)
                u.ob[c0 + c][w0 + p] = acc[hl][p][c];
        __syncthreads();
        float* vb = votes + (size_t)(b * 30 + (h0 + hl)) * SLAB + (size_t)d * (256 * 32);
        #pragma unroll
        for (int j = 0; j < 32; ++j) {
            int idx = t + j * 256;       // = co*32 + wc
            int co = idx >> 5, wc = idx & 31;
            vb[idx] = u.ob[co][wc];
        }
    }
}

// ---------------------------------------------------------------------------
// Kernel 2: dynamic routing per (b,h) row. 256 threads, 8 groups of 32 lanes
// (lane = w). logits/route/act in LDS. 3 iterations.
// ---------------------------------------------------------------------------
__global__ __launch_bounds__(256) void routing_kernel(
    const float* __restrict__ votes, const float* __restrict__ bias,
    float* __restrict__ out)
{
    const int h = blockIdx.x;    // 30
    const int b = blockIdx.y;    // 0..15 (chunk-local)
    const int t = threadIdx.x;

    __shared__ float logits[8][16][30];
    __shared__ float route [8][16][30];
    __shared__ float act   [16][16][31];
    __shared__ float bs[256];

    const float* vb = votes + (size_t)(b * 30 + h) * SLAB;

    bs[t] = bias[t];
    for (int j = t; j < 8 * 16 * 30; j += 256) (&logits[0][0][0])[j] = 0.f;
    __syncthreads();

    const int g  = t >> 5;       // 0..7
    const int w  = t & 31;       // lane within group; valid if < 30
    const bool wa = (w < 30);

    for (int it = 0; it < 3; ++it) {
        // ---- Phase A: route = softmax_o(logits) ; threads = (i,w) pairs
        if (t < 240) {
            int ii = t / 30, ww = t - ii * 30;
            float l[16], m = -1e30f;
            #pragma unroll
            for (int o = 0; o < 16; ++o) { l[o] = logits[ii][o][ww]; m = fmaxf(m, l[o]); }
            float s = 0.f;
            #pragma unroll
            for (int o = 0; o < 16; ++o) { l[o] = __expf(l[o] - m); s += l[o]; }
            float inv = 1.f / s;
            #pragma unroll
            for (int o = 0; o < 16; ++o) route[ii][o][ww] = l[o] * inv;
        }
        __syncthreads();

        // ---- Phase B: preact = sum_i route*votes + bias ; squash over w
        #pragma unroll
        for (int oh = 0; oh < 2; ++oh) {
            int o = g * 2 + oh;
            float r[8];
            #pragma unroll
            for (int i = 0; i < 8; ++i) r[i] = wa ? route[i][o][w] : 0.f;
            #pragma unroll
            for (int a = 0; a < 16; ++a) {
                float pre = bs[o * 16 + a];
                #pragma unroll
                for (int i = 0; i < 8; ++i) {
                    float v = vb[((i * 256 + o * 16 + a) << 5) + w];
                    pre += r[i] * v;
                }
                if (!wa) pre = 0.f;
                float s2 = pre * pre;
                #pragma unroll
                for (int mlane = 1; mlane < 32; mlane <<= 1)
                    s2 += __shfl_xor(s2, mlane, 32);
                float scale = s2 / ((1.f + s2) * sqrtf(s2 + 1e-7f));
                if (wa) act[o][a][w] = scale * pre;
            }
        }
        __syncthreads();

        // ---- Phase C: agreement logits[i,o,w] += sum_a votes*act (i = g)
        if (it < 2) {
            if (wa) {
                #pragma unroll
                for (int o = 0; o < 16; ++o) {
                    float s = 0.f;
                    #pragma unroll
                    for (int a = 0; a < 16; ++a) {
                        float v = vb[((g * 256 + o * 16 + a) << 5) + w];
                        s += v * act[o][a][w];
                    }
                    logits[g][o][w] += s;
                }
            }
            __syncthreads();
        }
    }

    // ---- output: out[b,h,w,o,a] ; coalesced, thread = (o,a) flat
    float* ob = out + (size_t)((b * 30 + h) * 30) * 256;
    #pragma unroll 1
    for (int wj = 0; wj < 30; ++wj)
        ob[wj * 256 + t] = act[t >> 4][t & 15][wj];
}

extern "C" void kernel_launch(void* const* d_in, const int* in_sizes, int n_in,
                              void* d_out, int out_size, void* d_ws, size_t ws_size,
                              hipStream_t stream)
{
    const float* x    = (const float*)d_in[0];  // [32,32,32,8,16]
    const float* Wt   = (const float*)d_in[1];  // [16,3,3,1,256]
    const float* bias = (const float*)d_in[2];  // [16,16,1,1]
    float* out = (float*)d_out;                 // [32,30,30,16,16]
    float* votes = (float*)d_ws;                // 125,829,120 bytes per chunk

    for (int c = 0; c < 2; ++c) {
        const float* xc = x   + (size_t)c * NBC * (128 * 1024);
        float*       oc = out + (size_t)c * NBC * (30 * 30 * 256);
        // stream ordering serializes conv -> routing -> next chunk
        conv_votes_kernel<<<dim3(NBC, 8, 15), 256, 0, stream>>>(xc, Wt, votes);
        routing_kernel<<<dim3(30, NBC), 256, 0, stream>>>(votes, bias, oc);
    }
}

// Round 3
// 826.071 us; speedup vs baseline: 1.8411x; 1.8411x over previous
//
#include <hip/hip_runtime.h>
#include <hip/hip_bf16.h>

// Problem constants
#define NBC  16      // batches per chunk (2 chunks)
// votes layout per chunk: [b(16)][h(30)][i(8)][w(32)][oa(256)] fp32
// per (b,h,i) region = 32*256 = 8192 floats (32 KB); chunk = 125,829,120 B
#define IRS  8192

// ---------------------------------------------------------------------------
// Kernel 1: conv -> votes (fp32), votes[b,h][i=d][w][co], float4 stores
// conv[b,co,d,hc,wc] = sum_{kd<16,kh<3,kw<3} xbuf[b, d*16+kd, hc+kh, wc+kw]*W[kd,kh,kw,0,co]
// ---------------------------------------------------------------------------
__global__ __launch_bounds__(256) void conv_votes_kernel(
    const float* __restrict__ x, const float* __restrict__ Wt,
    float* __restrict__ votes)
{
    const int b  = blockIdx.x;     // 0..15 (chunk-local)
    const int d  = blockIdx.y;     // 8
    const int h0 = blockIdx.z * 2; // 0,2,..,28
    const int t  = threadIdx.x;

    __shared__ union {
        struct {
            float xs[16][4][36];  // [kd][row][col padded]
            float ws[9][256];     // [tap][co] for current kd
        } s;
        float ob[32][264];        // transpose buffer [w][co padded]
    } u;

    // stage x rows once: 16*4*36 = 2304 entries
    {
        const float* xb = x + (size_t)b * (128 * 1024) + (size_t)d * (16 * 1024);
        #pragma unroll
        for (int j = 0; j < 9; ++j) {
            int idx = t + j * 256;
            int kd  = idx / 144;
            int rem = idx - kd * 144;
            int r   = rem / 36;
            int z   = rem - r * 36;
            float v = 0.f;
            if (z < 32) v = xb[kd * 1024 + (h0 + r) * 32 + z];
            u.s.xs[kd][r][z] = v;
        }
    }

    const int lane = t & 63;
    const int wg   = t >> 6;        // wc group (uniform per wave)
    const int c0   = lane * 4;      // co quad base
    const int w0   = wg * 8;        // wc base

    float acc[2][8][4];
    #pragma unroll
    for (int hl = 0; hl < 2; ++hl)
        #pragma unroll
        for (int p = 0; p < 8; ++p)
            #pragma unroll
            for (int c = 0; c < 4; ++c) acc[hl][p][c] = 0.f;

    for (int kd = 0; kd < 16; ++kd) {
        __syncthreads();
        #pragma unroll
        for (int j = 0; j < 9; ++j)
            u.s.ws[j][t] = Wt[(kd * 9 + j) * 256 + t];
        __syncthreads();

        #pragma unroll
        for (int kh = 0; kh < 3; ++kh) {
            float xr[2][12];
            #pragma unroll
            for (int hl = 0; hl < 2; ++hl) {
                float4 a4 = *(const float4*)&u.s.xs[kd][kh + hl][w0];
                float4 b4 = *(const float4*)&u.s.xs[kd][kh + hl][w0 + 4];
                float4 c4 = *(const float4*)&u.s.xs[kd][kh + hl][w0 + 8];
                xr[hl][0] = a4.x; xr[hl][1] = a4.y; xr[hl][2]  = a4.z; xr[hl][3]  = a4.w;
                xr[hl][4] = b4.x; xr[hl][5] = b4.y; xr[hl][6]  = b4.z; xr[hl][7]  = b4.w;
                xr[hl][8] = c4.x; xr[hl][9] = c4.y; xr[hl][10] = c4.z; xr[hl][11] = c4.w;
            }
            #pragma unroll
            for (int kw = 0; kw < 3; ++kw) {
                float4 wq = *(const float4*)&u.s.ws[kh * 3 + kw][c0];
                #pragma unroll
                for (int hl = 0; hl < 2; ++hl)
                    #pragma unroll
                    for (int p = 0; p < 8; ++p) {
                        float xv = xr[hl][kw + p];
                        acc[hl][p][0] += xv * wq.x;
                        acc[hl][p][1] += xv * wq.y;
                        acc[hl][p][2] += xv * wq.z;
                        acc[hl][p][3] += xv * wq.w;
                    }
            }
        }
    }

    // epilogue: LDS transpose to [w][co], then float4 (16B) coalesced stores
    #pragma unroll 1
    for (int hl = 0; hl < 2; ++hl) {
        __syncthreads();
        #pragma unroll
        for (int p = 0; p < 8; ++p) {
            float4 v4 = make_float4(acc[hl][p][0], acc[hl][p][1],
                                    acc[hl][p][2], acc[hl][p][3]);
            *(float4*)&u.ob[w0 + p][c0] = v4;     // contiguous per wave
        }
        __syncthreads();
        float* vb = votes + (size_t)(((b * 30 + h0 + hl) * 8) + d) * IRS;
        #pragma unroll
        for (int j = 0; j < 8; ++j) {
            int e  = (t + j * 256) * 4;           // elem base within 8192
            int w  = e >> 8;
            int co = e & 255;
            *(float4*)&vb[e] = *(const float4*)&u.ob[w][co];  // 1KB/wave/instr
        }
    }
}

// ---------------------------------------------------------------------------
// Kernel 2: routing. Block per (b,h). Phase B: thread = (o,a), serial squash
// in registers, coalesced streaming loads. Phase C: thread = (i,w),
// per-thread-contiguous reads (L2-hot).
// ---------------------------------------------------------------------------
__global__ __launch_bounds__(256) void routing_kernel(
    const float* __restrict__ votes, const float* __restrict__ bias,
    float* __restrict__ out)
{
    const int h = blockIdx.x;    // 30
    const int b = blockIdx.y;    // 0..15 (chunk-local)
    const int t = threadIdx.x;
    const int o = t >> 4;        // thread's output capsule (phase B)

    __shared__ float route [8 * 16 * 33];   // [i][o][w] stride 33 (bank-clean)
    __shared__ float logits[8 * 16 * 32];   // [i][o][w] stride 32
    __shared__ float act   [256 * 31];      // [oa][w] stride 31 (bank-clean)

    const float* vb = votes + (size_t)((b * 30 + h) * 8) * IRS;
    const float bias_t = bias[t];           // t = o*16+a matches [16][16]

    for (int j = t; j < 8 * 16 * 32; j += 256) logits[j] = 0.f;
    __syncthreads();

    const int iA = t / 30;                  // phase A/C mapping (t<240)
    const int wA = t - iA * 30;

    float pre[30];
    float scale = 0.f;

    for (int it = 0; it < 3; ++it) {
        // ---- Phase A: route = softmax_o(logits); threads (i,w)
        if (t < 240) {
            float l[16], m = -1e30f;
            #pragma unroll
            for (int oo = 0; oo < 16; ++oo) {
                l[oo] = logits[(iA * 16 + oo) * 32 + wA];
                m = fmaxf(m, l[oo]);
            }
            float s = 0.f;
            #pragma unroll
            for (int oo = 0; oo < 16; ++oo) { l[oo] = __expf(l[oo] - m); s += l[oo]; }
            float inv = 1.f / s;
            #pragma unroll
            for (int oo = 0; oo < 16; ++oo)
                route[(iA * 16 + oo) * 33 + wA] = l[oo] * inv;
        }
        __syncthreads();

        // ---- Phase B: thread (o,a): pre[w] = bias + sum_i route*votes
        #pragma unroll
        for (int w = 0; w < 30; ++w) pre[w] = bias_t;
        #pragma unroll
        for (int i = 0; i < 8; ++i) {
            const float* p = vb + i * IRS + t;          // stride-256 stream
            const float* r = &route[(i * 16 + o) * 33]; // LDS broadcast
            #pragma unroll
            for (int w = 0; w < 30; ++w)
                pre[w] = fmaf(r[w], p[w * 256], pre[w]); // no dep chains
        }
        float s2 = 0.f;
        #pragma unroll
        for (int w = 0; w < 30; ++w) s2 = fmaf(pre[w], pre[w], s2);
        scale = s2 / ((1.f + s2) * sqrtf(s2 + 1e-7f));

        if (it < 2) {
            #pragma unroll
            for (int w = 0; w < 30; ++w) act[t * 31 + w] = scale * pre[w];
            __syncthreads();
            // ---- Phase C: thread (i,w): logits[i,o,w] += sum_a v*act
            if (t < 240) {
                const float* vr = vb + iA * IRS + wA * 256;  // 1KB contiguous
                #pragma unroll
                for (int oo = 0; oo < 16; ++oo) {
                    float s = 0.f;
                    #pragma unroll
                    for (int aa = 0; aa < 16; ++aa)
                        s = fmaf(vr[oo * 16 + aa], act[(oo * 16 + aa) * 31 + wA], s);
                    logits[(iA * 16 + oo) * 32 + wA] += s;
                }
            }
            __syncthreads();
        }
    }

    // ---- output: out[b,h,w,o,a] directly from registers, coalesced
    float* ob = out + (size_t)((b * 30 + h) * 30) * 256;
    #pragma unroll
    for (int w = 0; w < 30; ++w) ob[w * 256 + t] = scale * pre[w];
}

extern "C" void kernel_launch(void* const* d_in, const int* in_sizes, int n_in,
                              void* d_out, int out_size, void* d_ws, size_t ws_size,
                              hipStream_t stream)
{
    const float* x    = (const float*)d_in[0];  // [32,32,32,8,16]
    const float* Wt   = (const float*)d_in[1];  // [16,3,3,1,256]
    const float* bias = (const float*)d_in[2];  // [16,16,1,1]
    float* out = (float*)d_out;                 // [32,30,30,16,16]
    float* votes = (float*)d_ws;                // 125,829,120 B per chunk

    for (int c = 0; c < 2; ++c) {
        const float* xc = x   + (size_t)c * NBC * (128 * 1024);
        float*       oc = out + (size_t)c * NBC * (30 * 30 * 256);
        conv_votes_kernel<<<dim3(NBC, 8, 15), 256, 0, stream>>>(xc, Wt, votes);
        routing_kernel<<<dim3(30, NBC), 256, 0, stream>>>(votes, bias, oc);
    }
}

// Round 5
// 454.274 us; speedup vs baseline: 3.3479x; 1.8184x over previous
//
#include <hip/hip_runtime.h>
#include <hip/hip_bf16.h>

typedef float f32x4 __attribute__((ext_vector_type(4)));

// Problem constants
#define NBC  16      // batches per chunk (2 chunks)
// votes layout per chunk: [b(16)][h(30)][i(8)][w(32)][oa(256)] fp32
// per (b,h,i) region = 32*256 = 8192 floats (32 KB); chunk = 125,829,120 B
#define IRS  8192

// ---------------------------------------------------------------------------
// Kernel 1: conv -> votes (fp32), votes[b,h][i=d][w][co]
// conv[b,co,d,hc,wc] = sum_{kd<16,kh<3,kw<3} xbuf[b, d*16+kd, hc+kh, wc+kw]*W[kd,kh,kw,0,co]
// W read directly from global as float4 (L1/L2-hot); x staged once in LDS.
// launch_bounds(256,2): VGPR cap 256 -> no accumulator spills to scratch.
// ---------------------------------------------------------------------------
__global__ __launch_bounds__(256, 2) void conv_votes_kernel(
    const float* __restrict__ x, const float* __restrict__ Wt,
    float* __restrict__ votes)
{
    const int b  = blockIdx.x;     // 0..15 (chunk-local)
    const int d  = blockIdx.y;     // 8
    const int h0 = blockIdx.z * 2; // 0,2,..,28
    const int t  = threadIdx.x;

    __shared__ union {
        float xs[16][4][36];  // [kd][row][col padded] rows h0..h0+3
        float ob[32][264];    // transpose buffer [w][co padded]
    } u;

    // stage x rows once: 16*4*36 = 2304 entries
    {
        const float* xb = x + (size_t)b * (128 * 1024) + (size_t)d * (16 * 1024);
        #pragma unroll
        for (int j = 0; j < 9; ++j) {
            int idx = t + j * 256;
            int kd  = idx / 144;
            int rem = idx - kd * 144;
            int r   = rem / 36;
            int z   = rem - r * 36;
            float v = 0.f;
            if (z < 32) v = xb[kd * 1024 + (h0 + r) * 32 + z];
            u.xs[kd][r][z] = v;
        }
    }

    const int lane = t & 63;
    const int wg   = t >> 6;        // wc group (uniform per wave)
    const int c0   = lane * 4;      // co quad base
    const int w0   = wg * 8;        // wc base

    float acc[2][8][4];
    #pragma unroll
    for (int hl = 0; hl < 2; ++hl)
        #pragma unroll
        for (int p = 0; p < 8; ++p)
            #pragma unroll
            for (int c = 0; c < 4; ++c) acc[hl][p][c] = 0.f;

    __syncthreads();   // xs ready

    for (int kd = 0; kd < 16; ++kd) {
        #pragma unroll
        for (int kh = 0; kh < 3; ++kh) {
            // W quads for the 3 kw taps of this (kd,kh), straight from global
            const float* wp = Wt + (size_t)(kd * 9 + kh * 3) * 256 + c0;
            float4 q0 = *(const float4*)(wp);
            float4 q1 = *(const float4*)(wp + 256);
            float4 q2 = *(const float4*)(wp + 512);

            float xr[2][12];
            #pragma unroll
            for (int hl = 0; hl < 2; ++hl) {
                float4 a4 = *(const float4*)&u.xs[kd][kh + hl][w0];
                float4 b4 = *(const float4*)&u.xs[kd][kh + hl][w0 + 4];
                float4 c4 = *(const float4*)&u.xs[kd][kh + hl][w0 + 8];
                xr[hl][0] = a4.x; xr[hl][1] = a4.y; xr[hl][2]  = a4.z; xr[hl][3]  = a4.w;
                xr[hl][4] = b4.x; xr[hl][5] = b4.y; xr[hl][6]  = b4.z; xr[hl][7]  = b4.w;
                xr[hl][8] = c4.x; xr[hl][9] = c4.y; xr[hl][10] = c4.z; xr[hl][11] = c4.w;
            }
            #pragma unroll
            for (int hl = 0; hl < 2; ++hl)
                #pragma unroll
                for (int p = 0; p < 8; ++p) {
                    float x0 = xr[hl][p + 0];
                    float x1 = xr[hl][p + 1];
                    float x2 = xr[hl][p + 2];
                    acc[hl][p][0] = fmaf(x0, q0.x, fmaf(x1, q1.x, fmaf(x2, q2.x, acc[hl][p][0])));
                    acc[hl][p][1] = fmaf(x0, q0.y, fmaf(x1, q1.y, fmaf(x2, q2.y, acc[hl][p][1])));
                    acc[hl][p][2] = fmaf(x0, q0.z, fmaf(x1, q1.z, fmaf(x2, q2.z, acc[hl][p][2])));
                    acc[hl][p][3] = fmaf(x0, q0.w, fmaf(x1, q1.w, fmaf(x2, q2.w, acc[hl][p][3])));
                }
        }
    }

    // epilogue: LDS transpose to [w][co], then nontemporal float4 stores
    #pragma unroll 1
    for (int hl = 0; hl < 2; ++hl) {
        __syncthreads();    // hl=0: everyone done reading xs (union reuse)
        #pragma unroll
        for (int p = 0; p < 8; ++p) {
            float4 v4 = make_float4(acc[hl][p][0], acc[hl][p][1],
                                    acc[hl][p][2], acc[hl][p][3]);
            *(float4*)&u.ob[w0 + p][c0] = v4;
        }
        __syncthreads();
        float* vb = votes + (size_t)(((b * 30 + h0 + hl) * 8) + d) * IRS;
        #pragma unroll
        for (int j = 0; j < 8; ++j) {
            int e  = (t + j * 256) * 4;           // elem base within 8192
            int w  = e >> 8;
            int co = e & 255;
            f32x4 v4 = *(const f32x4*)&u.ob[w][co];
            __builtin_nontemporal_store(v4, (f32x4*)&vb[e]);  // keep L2 clean
        }
    }
}

// ---------------------------------------------------------------------------
// Kernel 2: routing. Block per (b,h). Phase B: thread = (o,a), serial squash
// in registers, coalesced streaming loads. Phase C: thread = (i,w),
// per-thread-contiguous reads (L2-hot).
// ---------------------------------------------------------------------------
__global__ __launch_bounds__(256) void routing_kernel(
    const float* __restrict__ votes, const float* __restrict__ bias,
    float* __restrict__ out)
{
    const int h = blockIdx.x;    // 30
    const int b = blockIdx.y;    // 0..15 (chunk-local)
    const int t = threadIdx.x;
    const int o = t >> 4;        // thread's output capsule (phase B)

    __shared__ float route [8 * 16 * 33];   // [i][o][w] stride 33 (bank-clean)
    __shared__ float logits[8 * 16 * 32];   // [i][o][w] stride 32
    __shared__ float act   [256 * 31];      // [oa][w] stride 31 (bank-clean)

    const float* vb = votes + (size_t)((b * 30 + h) * 8) * IRS;
    const float bias_t = bias[t];           // t = o*16+a matches [16][16]

    for (int j = t; j < 8 * 16 * 32; j += 256) logits[j] = 0.f;
    __syncthreads();

    const int iA = t / 30;                  // phase A/C mapping (t<240)
    const int wA = t - iA * 30;

    float pre[30];
    float scale = 0.f;

    for (int it = 0; it < 3; ++it) {
        // ---- Phase A: route = softmax_o(logits); threads (i,w)
        if (t < 240) {
            float l[16], m = -1e30f;
            #pragma unroll
            for (int oo = 0; oo < 16; ++oo) {
                l[oo] = logits[(iA * 16 + oo) * 32 + wA];
                m = fmaxf(m, l[oo]);
            }
            float s = 0.f;
            #pragma unroll
            for (int oo = 0; oo < 16; ++oo) { l[oo] = __expf(l[oo] - m); s += l[oo]; }
            float inv = 1.f / s;
            #pragma unroll
            for (int oo = 0; oo < 16; ++oo)
                route[(iA * 16 + oo) * 33 + wA] = l[oo] * inv;
        }
        __syncthreads();

        // ---- Phase B: thread (o,a): pre[w] = bias + sum_i route*votes
        #pragma unroll
        for (int w = 0; w < 30; ++w) pre[w] = bias_t;
        #pragma unroll
        for (int i = 0; i < 8; ++i) {
            const float* p = vb + i * IRS + t;          // stride-256 stream
            const float* r = &route[(i * 16 + o) * 33]; // LDS broadcast
            #pragma unroll
            for (int w = 0; w < 30; ++w)
                pre[w] = fmaf(r[w], p[w * 256], pre[w]); // no dep chains
        }
        float s2 = 0.f;
        #pragma unroll
        for (int w = 0; w < 30; ++w) s2 = fmaf(pre[w], pre[w], s2);
        scale = s2 / ((1.f + s2) * sqrtf(s2 + 1e-7f));

        if (it < 2) {
            #pragma unroll
            for (int w = 0; w < 30; ++w) act[t * 31 + w] = scale * pre[w];
            __syncthreads();
            // ---- Phase C: thread (i,w): logits[i,o,w] += sum_a v*act
            if (t < 240) {
                const float* vr = vb + iA * IRS + wA * 256;  // 1KB contiguous
                #pragma unroll
                for (int oo = 0; oo < 16; ++oo) {
                    float s = 0.f;
                    #pragma unroll
                    for (int aa = 0; aa < 16; ++aa)
                        s = fmaf(vr[oo * 16 + aa], act[(oo * 16 + aa) * 31 + wA], s);
                    logits[(iA * 16 + oo) * 32 + wA] += s;
                }
            }
            __syncthreads();
        }
    }

    // ---- output: out[b,h,w,o,a] directly from registers, coalesced
    float* ob = out + (size_t)((b * 30 + h) * 30) * 256;
    #pragma unroll
    for (int w = 0; w < 30; ++w) ob[w * 256 + t] = scale * pre[w];
}

extern "C" void kernel_launch(void* const* d_in, const int* in_sizes, int n_in,
                              void* d_out, int out_size, void* d_ws, size_t ws_size,
                              hipStream_t stream)
{
    const float* x    = (const float*)d_in[0];  // [32,32,32,8,16]
    const float* Wt   = (const float*)d_in[1];  // [16,3,3,1,256]
    const float* bias = (const float*)d_in[2];  // [16,16,1,1]
    float* out = (float*)d_out;                 // [32,30,30,16,16]
    float* votes = (float*)d_ws;                // 125,829,120 B per chunk

    for (int c = 0; c < 2; ++c) {
        const float* xc = x   + (size_t)c * NBC * (128 * 1024);
        float*       oc = out + (size_t)c * NBC * (30 * 30 * 256);
        conv_votes_kernel<<<dim3(NBC, 8, 15), 256, 0, stream>>>(xc, Wt, votes);
        routing_kernel<<<dim3(30, NBC), 256, 0, stream>>>(votes, bias, oc);
    }
}

// Round 6
// 357.544 us; speedup vs baseline: 4.2536x; 1.2705x over previous
//
#include <hip/hip_runtime.h>
#include <hip/hip_bf16.h>

typedef float f32x4 __attribute__((ext_vector_type(4)));

// Problem constants
#define NBC  16      // batches per chunk (2 chunks)
// votes layout per chunk: [b(16)][h(30)][i(8)][w(32)][oa(256)] fp32
// per (b,h,i) region = 32*256 = 8192 floats (32 KB); chunk = 125,829,120 B
#define IRS  8192

// ---------------------------------------------------------------------------
// Kernel 1: conv -> votes (fp32), votes[b,h][i=d][w][co]
// conv[b,co,d,hc,wc] = sum_{kd<16,kh<3,kw<3} xbuf[b, d*16+kd, hc+kh, wc+kw]*W[kd,kh,kw,0,co]
// x staged once in LDS (9.2KB only -> high occupancy); W double-buffered from
// global (L2-hot) one (kd,kh) tap ahead; acc stored directly as float4
// (each wave's 64 lanes cover co 0..255 contiguously -> 1KB/instr, no LDS
// transpose needed).
// ---------------------------------------------------------------------------
__global__ __launch_bounds__(256, 2) void conv_votes_kernel(
    const float* __restrict__ x, const float* __restrict__ Wt,
    float* __restrict__ votes)
{
    const int b  = blockIdx.x;     // 0..15 (chunk-local)
    const int d  = blockIdx.y;     // 8
    const int h0 = blockIdx.z * 2; // 0,2,..,28
    const int t  = threadIdx.x;

    __shared__ float xs[16][4][36];  // [kd][row][col padded] rows h0..h0+3

    // stage x rows once: 16*4*36 = 2304 entries
    {
        const float* xb = x + (size_t)b * (128 * 1024) + (size_t)d * (16 * 1024);
        #pragma unroll
        for (int j = 0; j < 9; ++j) {
            int idx = t + j * 256;
            int kd  = idx / 144;
            int rem = idx - kd * 144;
            int r   = rem / 36;
            int z   = rem - r * 36;
            float v = 0.f;
            if (z < 32) v = xb[kd * 1024 + (h0 + r) * 32 + z];
            xs[kd][r][z] = v;
        }
    }

    const int lane = t & 63;
    const int wg   = t >> 6;        // wc group (uniform per wave)
    const int c0   = lane * 4;      // co quad base
    const int w0   = wg * 8;        // wc base

    float acc[2][8][4];
    #pragma unroll
    for (int hl = 0; hl < 2; ++hl)
        #pragma unroll
        for (int p = 0; p < 8; ++p)
            #pragma unroll
            for (int c = 0; c < 4; ++c) acc[hl][p][c] = 0.f;

    const float* wbase = Wt + c0;
    // prefetch tap 0
    float4 q0 = *(const float4*)(wbase);
    float4 q1 = *(const float4*)(wbase + 256);
    float4 q2 = *(const float4*)(wbase + 512);

    __syncthreads();   // xs ready

    for (int kd = 0; kd < 16; ++kd) {
        #pragma unroll
        for (int kh = 0; kh < 3; ++kh) {
            // current tap quads
            float4 p0 = q0, p1 = q1, p2 = q2;
            // prefetch next (kd,kh) tap while FMAs below execute
            int nxt = kd * 3 + kh + 1;
            if (nxt < 48) {
                const float* wp = wbase + (size_t)nxt * 768;
                q0 = *(const float4*)(wp);
                q1 = *(const float4*)(wp + 256);
                q2 = *(const float4*)(wp + 512);
            }

            float xr[2][12];
            #pragma unroll
            for (int hl = 0; hl < 2; ++hl) {
                float4 a4 = *(const float4*)&xs[kd][kh + hl][w0];
                float4 b4 = *(const float4*)&xs[kd][kh + hl][w0 + 4];
                float4 c4 = *(const float4*)&xs[kd][kh + hl][w0 + 8];
                xr[hl][0] = a4.x; xr[hl][1] = a4.y; xr[hl][2]  = a4.z; xr[hl][3]  = a4.w;
                xr[hl][4] = b4.x; xr[hl][5] = b4.y; xr[hl][6]  = b4.z; xr[hl][7]  = b4.w;
                xr[hl][8] = c4.x; xr[hl][9] = c4.y; xr[hl][10] = c4.z; xr[hl][11] = c4.w;
            }
            #pragma unroll
            for (int hl = 0; hl < 2; ++hl)
                #pragma unroll
                for (int p = 0; p < 8; ++p) {
                    float x0 = xr[hl][p + 0];
                    float x1 = xr[hl][p + 1];
                    float x2 = xr[hl][p + 2];
                    acc[hl][p][0] = fmaf(x0, p0.x, fmaf(x1, p1.x, fmaf(x2, p2.x, acc[hl][p][0])));
                    acc[hl][p][1] = fmaf(x0, p0.y, fmaf(x1, p1.y, fmaf(x2, p2.y, acc[hl][p][1])));
                    acc[hl][p][2] = fmaf(x0, p0.z, fmaf(x1, p1.z, fmaf(x2, p2.z, acc[hl][p][2])));
                    acc[hl][p][3] = fmaf(x0, p0.w, fmaf(x1, p1.w, fmaf(x2, p2.w, acc[hl][p][3])));
                }
        }
    }

    // epilogue: direct register->global stores; per (hl,p) the wave's 64 lanes
    // cover votes[..][w0+p][0..255] = 1KB contiguous
    #pragma unroll
    for (int hl = 0; hl < 2; ++hl) {
        float* vb = votes + (size_t)(((b * 30 + h0 + hl) * 8) + d) * IRS;
        #pragma unroll
        for (int p = 0; p < 8; ++p) {
            f32x4 v4 = { acc[hl][p][0], acc[hl][p][1], acc[hl][p][2], acc[hl][p][3] };
            *(f32x4*)&vb[(w0 + p) * 256 + c0] = v4;
        }
    }
}

// ---------------------------------------------------------------------------
// Kernel 2: routing. Block per (b,h). Phase B: thread = (o,a), serial squash
// in registers, coalesced streaming loads. Phase C: thread = (i,w),
// per-thread-contiguous reads (L2-hot).
// ---------------------------------------------------------------------------
__global__ __launch_bounds__(256) void routing_kernel(
    const float* __restrict__ votes, const float* __restrict__ bias,
    float* __restrict__ out)
{
    const int h = blockIdx.x;    // 30
    const int b = blockIdx.y;    // 0..15 (chunk-local)
    const int t = threadIdx.x;
    const int o = t >> 4;        // thread's output capsule (phase B)

    __shared__ float route [8 * 16 * 33];   // [i][o][w] stride 33 (bank-clean)
    __shared__ float logits[8 * 16 * 32];   // [i][o][w] stride 32
    __shared__ float act   [256 * 31];      // [oa][w] stride 31 (bank-clean)

    const float* vb = votes + (size_t)((b * 30 + h) * 8) * IRS;
    const float bias_t = bias[t];           // t = o*16+a matches [16][16]

    for (int j = t; j < 8 * 16 * 32; j += 256) logits[j] = 0.f;
    __syncthreads();

    const int iA = t / 30;                  // phase A/C mapping (t<240)
    const int wA = t - iA * 30;

    float pre[30];
    float scale = 0.f;

    for (int it = 0; it < 3; ++it) {
        // ---- Phase A: route = softmax_o(logits); threads (i,w)
        if (t < 240) {
            float l[16], m = -1e30f;
            #pragma unroll
            for (int oo = 0; oo < 16; ++oo) {
                l[oo] = logits[(iA * 16 + oo) * 32 + wA];
                m = fmaxf(m, l[oo]);
            }
            float s = 0.f;
            #pragma unroll
            for (int oo = 0; oo < 16; ++oo) { l[oo] = __expf(l[oo] - m); s += l[oo]; }
            float inv = 1.f / s;
            #pragma unroll
            for (int oo = 0; oo < 16; ++oo)
                route[(iA * 16 + oo) * 33 + wA] = l[oo] * inv;
        }
        __syncthreads();

        // ---- Phase B: thread (o,a): pre[w] = bias + sum_i route*votes
        #pragma unroll
        for (int w = 0; w < 30; ++w) pre[w] = bias_t;
        #pragma unroll
        for (int i = 0; i < 8; ++i) {
            const float* p = vb + i * IRS + t;          // stride-256 stream
            const float* r = &route[(i * 16 + o) * 33]; // LDS broadcast
            #pragma unroll
            for (int w = 0; w < 30; ++w)
                pre[w] = fmaf(r[w], p[w * 256], pre[w]); // no dep chains
        }
        float s2 = 0.f;
        #pragma unroll
        for (int w = 0; w < 30; ++w) s2 = fmaf(pre[w], pre[w], s2);
        scale = s2 / ((1.f + s2) * sqrtf(s2 + 1e-7f));

        if (it < 2) {
            #pragma unroll
            for (int w = 0; w < 30; ++w) act[t * 31 + w] = scale * pre[w];
            __syncthreads();
            // ---- Phase C: thread (i,w): logits[i,o,w] += sum_a v*act
            if (t < 240) {
                const float* vr = vb + iA * IRS + wA * 256;  // 1KB contiguous
                #pragma unroll
                for (int oo = 0; oo < 16; ++oo) {
                    float s = 0.f;
                    #pragma unroll
                    for (int aa = 0; aa < 16; ++aa)
                        s = fmaf(vr[oo * 16 + aa], act[(oo * 16 + aa) * 31 + wA], s);
                    logits[(iA * 16 + oo) * 32 + wA] += s;
                }
            }
            __syncthreads();
        }
    }

    // ---- output: out[b,h,w,o,a] directly from registers, coalesced
    float* ob = out + (size_t)((b * 30 + h) * 30) * 256;
    #pragma unroll
    for (int w = 0; w < 30; ++w) ob[w * 256 + t] = scale * pre[w];
}

extern "C" void kernel_launch(void* const* d_in, const int* in_sizes, int n_in,
                              void* d_out, int out_size, void* d_ws, size_t ws_size,
                              hipStream_t stream)
{
    const float* x    = (const float*)d_in[0];  // [32,32,32,8,16]
    const float* Wt   = (const float*)d_in[1];  // [16,3,3,1,256]
    const float* bias = (const float*)d_in[2];  // [16,16,1,1]
    float* out = (float*)d_out;                 // [32,30,30,16,16]
    float* votes = (float*)d_ws;                // 125,829,120 B per chunk

    for (int c = 0; c < 2; ++c) {
        const float* xc = x   + (size_t)c * NBC * (128 * 1024);
        float*       oc = out + (size_t)c * NBC * (30 * 30 * 256);
        conv_votes_kernel<<<dim3(NBC, 8, 15), 256, 0, stream>>>(xc, Wt, votes);
        routing_kernel<<<dim3(30, NBC), 256, 0, stream>>>(votes, bias, oc);
    }
}

// Round 7
// 239.104 us; speedup vs baseline: 6.3606x; 1.4954x over previous
//
#include <hip/hip_runtime.h>
#include <hip/hip_bf16.h>

typedef float    f32x4  __attribute__((ext_vector_type(4)));
typedef float    f32x16 __attribute__((ext_vector_type(16)));
typedef _Float16 f16x8  __attribute__((ext_vector_type(8)));

// Problem constants
#define NBC   16      // batches per chunk (2 chunks)
// votes layout per chunk: [b(16)][h(30)][i(8)][w(30)][co(256)] fp32
#define VSLAB 7680    // 30*256 floats per (b,h,i)
// chunk votes bytes = 16*30*8*7680*4 = 117,964,800 ; W_t fp16 [256][160] = 81,920 B after
#define WT_OFF 117964800

// ---------------------------------------------------------------------------
// Kernel 0: W [144][256] f32 -> W_t [256][160] fp16 (k-padded to 160)
// ---------------------------------------------------------------------------
__global__ __launch_bounds__(256) void prep_wt_kernel(
    const float* __restrict__ W, _Float16* __restrict__ wt)
{
    const int k = blockIdx.x;      // 0..143
    const int t = threadIdx.x;     // co
    wt[t * 160 + k] = (_Float16)W[k * 256 + t];
}

// ---------------------------------------------------------------------------
// Kernel 1: conv -> votes via MFMA fp16.
// Per block (b,d,h-pair): D[hw=64][co=256] = sum_{k<144} X[hw][k]*W[k][co]
//   X[hw=(hp,w)][k=(kd,kh,kw)] = x[b][d*16+kd][h0+hp+kh][w+kw]
// A-frag = X (M=hw), B-frag = W (N=co) -> D cols=co on consecutive lanes ->
// coalesced direct stores. 9 MFMA K-steps of 16. fp32 accumulation.
// ---------------------------------------------------------------------------
__global__ __launch_bounds__(256, 2) void conv_mfma_kernel(
    const float* __restrict__ x, const _Float16* __restrict__ wt,
    float* __restrict__ votes)
{
    const int b  = blockIdx.x;     // 0..15 (chunk-local)
    const int d  = blockIdx.y;     // 8
    const int h0 = blockIdx.z * 2; // 0,2,..,28
    const int t  = threadIdx.x;

    __shared__ float xs[16][4][36];                 // [kd][row][col pad] (9.2 KB)
    __shared__ alignas(16) _Float16 Xt[64 * 168];   // [hw][k pad 168]   (21 KB)

    const int lane = t & 63;
    const int wv   = t >> 6;       // wave 0..3
    const int l31  = lane & 31;
    const int kb   = lane >> 5;    // k-block 0/1
    const int hwt  = wv >> 1;      // hw tile = hp (0/1)
    const int cb   = (wv & 1) * 4; // co-tile base (0 or 4)

    // --- issue B prefetch for first co-tile immediately (no LDS dependency)
    f16x8 bfA[9], bfB[9];
    {
        const _Float16* wp = wt + (size_t)((cb * 32 + l31) * 160 + kb * 8);
        #pragma unroll
        for (int s = 0; s < 9; ++s) bfA[s] = *(const f16x8*)(wp + s * 16);
    }

    // --- stage x rows: 16*4*36 = 2304 entries (cols 32..35 zero)
    {
        const float* xb = x + (size_t)b * (128 * 1024) + (size_t)d * (16 * 1024);
        #pragma unroll
        for (int j = 0; j < 9; ++j) {
            int idx = t + j * 256;
            int kd  = idx / 144;
            int rem = idx - kd * 144;
            int r   = rem / 36;
            int z   = rem - r * 36;
            float v = 0.f;
            if (z < 32) v = xb[kd * 1024 + (h0 + r) * 32 + z];
            xs[kd][r][z] = v;
        }
    }
    __syncthreads();

    // --- im2col build: thread t -> hw = t>>2, k-range q*36..q*36+35
    {
        const int hw = t >> 2, q = t & 3;
        const int hp = hw >> 5, w = hw & 31;
        _Float16* xrow = &Xt[hw * 168 + q * 36];
        #pragma unroll
        for (int jj = 0; jj < 36; ++jj) {
            const int kd = 4 * q + (jj / 9);        // compile-time splits
            const int kh = (jj % 9) / 3;
            const int kw = jj % 3;
            xrow[jj] = (_Float16)xs[kd][hp + kh][w + kw];
        }
    }
    __syncthreads();

    // --- A-frags: 9 ds_read_b128, row = hwt*32 + l31, k = s*16 + kb*8
    f16x8 af[9];
    {
        const _Float16* ar = &Xt[(hwt * 32 + l31) * 168 + kb * 8];
        #pragma unroll
        for (int s = 0; s < 9; ++s) af[s] = *(const f16x8*)(ar + s * 16);
    }

    f32x16 acc[4];
    #pragma unroll
    for (int c = 0; c < 4; ++c)
        #pragma unroll
        for (int e = 0; e < 16; ++e) acc[c][e] = 0.f;

    // --- MFMA main loop: 4 co-tiles x 9 K-steps, B double-buffered
    #pragma unroll
    for (int cc = 0; cc < 4; ++cc) {
        if (cc < 3) {   // prefetch next co-tile's B frags
            const _Float16* wp = wt + (size_t)(((cb + cc + 1) * 32 + l31) * 160 + kb * 8);
            if ((cc & 1) == 0) {
                #pragma unroll
                for (int s = 0; s < 9; ++s) bfB[s] = *(const f16x8*)(wp + s * 16);
            } else {
                #pragma unroll
                for (int s = 0; s < 9; ++s) bfA[s] = *(const f16x8*)(wp + s * 16);
            }
        }
        #pragma unroll
        for (int s = 0; s < 9; ++s) {
            f16x8 bcur = ((cc & 1) == 0) ? bfA[s] : bfB[s];
            acc[cc] = __builtin_amdgcn_mfma_f32_32x32x16_f16(af[s], bcur, acc[cc], 0, 0, 0);
        }
    }

    // --- stores: D layout col(co)=l31, row(hw) = (r&3)+8*(r>>2)+4*kb
    float* vb = votes + (size_t)(((b * 30 + h0 + hwt) * 8) + d) * VSLAB;
    #pragma unroll
    for (int cc = 0; cc < 4; ++cc) {
        const int co = (cb + cc) * 32 + l31;
        #pragma unroll
        for (int r = 0; r < 16; ++r) {
            const int w = (r & 3) + 8 * (r >> 2) + 4 * kb;
            if (w < 30) vb[w * 256 + co] = acc[cc][r];
        }
    }
}

// ---------------------------------------------------------------------------
// Kernel 2: routing. Block per (b,h). Phase B: thread = (o,a), serial squash
// in registers, coalesced streaming loads. Phase C: thread = (i,w), L2-hot.
// ---------------------------------------------------------------------------
__global__ __launch_bounds__(256) void routing_kernel(
    const float* __restrict__ votes, const float* __restrict__ bias,
    float* __restrict__ out)
{
    const int h = blockIdx.x;    // 30
    const int b = blockIdx.y;    // 0..15 (chunk-local)
    const int t = threadIdx.x;
    const int o = t >> 4;        // thread's output capsule (phase B)

    __shared__ float route [8 * 16 * 33];   // [i][o][w] stride 33 (bank-clean)
    __shared__ float logits[8 * 16 * 32];   // [i][o][w] stride 32
    __shared__ float act   [256 * 31];      // [oa][w] stride 31 (bank-clean)

    const float* vb = votes + (size_t)((b * 30 + h) * 8) * VSLAB;
    const float bias_t = bias[t];           // t = o*16+a matches [16][16]

    for (int j = t; j < 8 * 16 * 32; j += 256) logits[j] = 0.f;
    __syncthreads();

    const int iA = t / 30;                  // phase A/C mapping (t<240)
    const int wA = t - iA * 30;

    float pre[30];
    float scale = 0.f;

    for (int it = 0; it < 3; ++it) {
        // ---- Phase A: route = softmax_o(logits); threads (i,w)
        if (t < 240) {
            float l[16], m = -1e30f;
            #pragma unroll
            for (int oo = 0; oo < 16; ++oo) {
                l[oo] = logits[(iA * 16 + oo) * 32 + wA];
                m = fmaxf(m, l[oo]);
            }
            float s = 0.f;
            #pragma unroll
            for (int oo = 0; oo < 16; ++oo) { l[oo] = __expf(l[oo] - m); s += l[oo]; }
            float inv = 1.f / s;
            #pragma unroll
            for (int oo = 0; oo < 16; ++oo)
                route[(iA * 16 + oo) * 33 + wA] = l[oo] * inv;
        }
        __syncthreads();

        // ---- Phase B: thread (o,a): pre[w] = bias + sum_i route*votes
        #pragma unroll
        for (int w = 0; w < 30; ++w) pre[w] = bias_t;
        #pragma unroll
        for (int i = 0; i < 8; ++i) {
            const float* p = vb + i * VSLAB + t;        // stride-256 stream
            const float* r = &route[(i * 16 + o) * 33]; // LDS broadcast
            #pragma unroll
            for (int w = 0; w < 30; ++w)
                pre[w] = fmaf(r[w], p[w * 256], pre[w]);
        }
        float s2 = 0.f;
        #pragma unroll
        for (int w = 0; w < 30; ++w) s2 = fmaf(pre[w], pre[w], s2);
        scale = s2 / ((1.f + s2) * sqrtf(s2 + 1e-7f));

        if (it < 2) {
            #pragma unroll
            for (int w = 0; w < 30; ++w) act[t * 31 + w] = scale * pre[w];
            __syncthreads();
            // ---- Phase C: thread (i,w): logits[i,o,w] += sum_a v*act
            if (t < 240) {
                const float* vr = vb + iA * VSLAB + wA * 256;  // 1KB contiguous
                #pragma unroll
                for (int oo = 0; oo < 16; ++oo) {
                    float s = 0.f;
                    #pragma unroll
                    for (int aa = 0; aa < 16; ++aa)
                        s = fmaf(vr[oo * 16 + aa], act[(oo * 16 + aa) * 31 + wA], s);
                    logits[(iA * 16 + oo) * 32 + wA] += s;
                }
            }
            __syncthreads();
        }
    }

    // ---- output: out[b,h,w,o,a] directly from registers, coalesced
    float* ob = out + (size_t)((b * 30 + h) * 30) * 256;
    #pragma unroll
    for (int w = 0; w < 30; ++w) ob[w * 256 + t] = scale * pre[w];
}

extern "C" void kernel_launch(void* const* d_in, const int* in_sizes, int n_in,
                              void* d_out, int out_size, void* d_ws, size_t ws_size,
                              hipStream_t stream)
{
    const float* x    = (const float*)d_in[0];  // [32,32,32,8,16]
    const float* Wt   = (const float*)d_in[1];  // [16,3,3,1,256] = [144][256]
    const float* bias = (const float*)d_in[2];  // [16,16,1,1]
    float* out = (float*)d_out;                 // [32,30,30,16,16]
    float*     votes = (float*)d_ws;            // 117,964,800 B per chunk
    _Float16*  wt_h  = (_Float16*)((char*)d_ws + WT_OFF);  // [256][160] fp16

    prep_wt_kernel<<<dim3(144), 256, 0, stream>>>(Wt, wt_h);

    for (int c = 0; c < 2; ++c) {
        const float* xc = x   + (size_t)c * NBC * (128 * 1024);
        float*       oc = out + (size_t)c * NBC * (30 * 30 * 256);
        conv_mfma_kernel<<<dim3(NBC, 8, 15), 256, 0, stream>>>(xc, wt_h, votes);
        routing_kernel<<<dim3(30, NBC), 256, 0, stream>>>(votes, bias, oc);
    }
}

// Round 8
// 138.833 us; speedup vs baseline: 10.9545x; 1.7222x over previous
//
#include <hip/hip_runtime.h>
#include <hip/hip_bf16.h>

typedef float    f32x4  __attribute__((ext_vector_type(4)));
typedef float    f32x16 __attribute__((ext_vector_type(16)));
typedef _Float16 f16x8  __attribute__((ext_vector_type(8)));
typedef _Float16 f16x2  __attribute__((ext_vector_type(2)));

// votes (fp16, full batch): [b(32)][h(30)][i(8)][w(30)][oa(256)]
// = 32*30*8*30*256*2 B = 117,964,800 B ; W_t fp16 [256][160] after it.
#define VSLAB  7680          // 30*256 fp16 per (b,h,i)
#define WT_OFF 117964800

// ---------------------------------------------------------------------------
// Kernel 0: W [144][256] f32 -> W_t [256][160] fp16 (k-padded to 160)
// ---------------------------------------------------------------------------
__global__ __launch_bounds__(256) void prep_wt_kernel(
    const float* __restrict__ W, _Float16* __restrict__ wt)
{
    const int k = blockIdx.x;      // 0..143
    const int t = threadIdx.x;     // co
    wt[t * 160 + k] = (_Float16)W[k * 256 + t];
}

// ---------------------------------------------------------------------------
// Kernel 1: conv -> votes via MFMA fp16 (fp32 accum), fp16 stores.
// Per block (b,d,h-pair): D[hw=64][co=256] = sum_{k<144} X[hw][k]*W[k][co]
// ---------------------------------------------------------------------------
__global__ __launch_bounds__(256, 2) void conv_mfma_kernel(
    const float* __restrict__ x, const _Float16* __restrict__ wt,
    _Float16* __restrict__ votes)
{
    const int b  = blockIdx.x;     // 0..31
    const int d  = blockIdx.y;     // 8
    const int h0 = blockIdx.z * 2; // 0,2,..,28
    const int t  = threadIdx.x;

    __shared__ float xs[16][4][36];                 // [kd][row][col pad] (9.2 KB)
    __shared__ alignas(16) _Float16 Xt[64 * 168];   // [hw][k pad 168]   (21 KB)

    const int lane = t & 63;
    const int wv   = t >> 6;       // wave 0..3
    const int l31  = lane & 31;
    const int kb   = lane >> 5;    // k-block 0/1
    const int hwt  = wv >> 1;      // hw tile = hp (0/1)
    const int cb   = (wv & 1) * 4; // co-tile base (0 or 4)

    // --- B prefetch for first co-tile (no LDS dependency)
    f16x8 bfA[9], bfB[9];
    {
        const _Float16* wp = wt + (size_t)((cb * 32 + l31) * 160 + kb * 8);
        #pragma unroll
        for (int s = 0; s < 9; ++s) bfA[s] = *(const f16x8*)(wp + s * 16);
    }

    // --- stage x rows: 16*4*36 = 2304 entries (cols 32..35 zero)
    {
        const float* xb = x + (size_t)b * (128 * 1024) + (size_t)d * (16 * 1024);
        #pragma unroll
        for (int j = 0; j < 9; ++j) {
            int idx = t + j * 256;
            int kd  = idx / 144;
            int rem = idx - kd * 144;
            int r   = rem / 36;
            int z   = rem - r * 36;
            float v = 0.f;
            if (z < 32) v = xb[kd * 1024 + (h0 + r) * 32 + z];
            xs[kd][r][z] = v;
        }
    }
    __syncthreads();

    // --- im2col build: thread t -> hw = t>>2, k-range q*36..q*36+35
    {
        const int hw = t >> 2, q = t & 3;
        const int hp = hw >> 5, w = hw & 31;
        _Float16* xrow = &Xt[hw * 168 + q * 36];
        #pragma unroll
        for (int jj = 0; jj < 36; ++jj) {
            const int kd = 4 * q + (jj / 9);
            const int kh = (jj % 9) / 3;
            const int kw = jj % 3;
            xrow[jj] = (_Float16)xs[kd][hp + kh][w + kw];
        }
    }
    __syncthreads();

    // --- A-frags: 9 ds_read_b128, row = hwt*32 + l31, k = s*16 + kb*8
    f16x8 af[9];
    {
        const _Float16* ar = &Xt[(hwt * 32 + l31) * 168 + kb * 8];
        #pragma unroll
        for (int s = 0; s < 9; ++s) af[s] = *(const f16x8*)(ar + s * 16);
    }

    f32x16 acc[4];
    #pragma unroll
    for (int c = 0; c < 4; ++c)
        #pragma unroll
        for (int e = 0; e < 16; ++e) acc[c][e] = 0.f;

    // --- MFMA main loop: 4 co-tiles x 9 K-steps, B double-buffered
    #pragma unroll
    for (int cc = 0; cc < 4; ++cc) {
        if (cc < 3) {
            const _Float16* wp = wt + (size_t)(((cb + cc + 1) * 32 + l31) * 160 + kb * 8);
            if ((cc & 1) == 0) {
                #pragma unroll
                for (int s = 0; s < 9; ++s) bfB[s] = *(const f16x8*)(wp + s * 16);
            } else {
                #pragma unroll
                for (int s = 0; s < 9; ++s) bfA[s] = *(const f16x8*)(wp + s * 16);
            }
        }
        #pragma unroll
        for (int s = 0; s < 9; ++s) {
            f16x8 bcur = ((cc & 1) == 0) ? bfA[s] : bfB[s];
            acc[cc] = __builtin_amdgcn_mfma_f32_32x32x16_f16(af[s], bcur, acc[cc], 0, 0, 0);
        }
    }

    // --- stores: D layout col(co)=l31, row(hw) = (r&3)+8*(r>>2)+4*kb
    _Float16* vb = votes + (size_t)(((b * 30 + h0 + hwt) * 8) + d) * VSLAB;
    #pragma unroll
    for (int cc = 0; cc < 4; ++cc) {
        const int co = (cb + cc) * 32 + l31;
        #pragma unroll
        for (int r = 0; r < 16; ++r) {
            const int w = (r & 3) + 8 * (r >> 2) + 4 * kb;
            if (w < 30) vb[w * 256 + co] = (_Float16)acc[cc][r];
        }
    }
}

// ---------------------------------------------------------------------------
// Kernel 2: routing, fully LDS-resident votes. Block per (b,h), 256 threads.
// Stage fp16 votes slab (122.9 KB) once -> 5 passes hit LDS only.
// vlds pitch 258: phase B lanes vary oa (2/word, clean); phase C lanes vary w
// (stride 129 words === 1 mod 32, clean for b32 reads).
// ---------------------------------------------------------------------------
__global__ __launch_bounds__(256) void routing_kernel(
    const _Float16* __restrict__ votes, const float* __restrict__ bias,
    float* __restrict__ out)
{
    const int h = blockIdx.x;    // 30
    const int b = blockIdx.y;    // 32
    const int t = threadIdx.x;
    const int o = t >> 4;        // phase-B thread's output capsule

    __shared__ _Float16 vlds  [8 * 30 * 258];   // 123,840 B
    __shared__ float    logits[8 * 16 * 31];    //  15,872 B (pitch 31)
    __shared__ _Float16 route16[8 * 16 * 30];   //   7,680 B
    __shared__ _Float16 act16 [30 * 258];       //  15,480 B   total ~162.9 KB

    // ---- stage votes slab: 7680 granules of 16B, coalesced
    {
        const _Float16* vg = votes + (size_t)(b * 30 + h) * (8 * VSLAB);
        #pragma unroll
        for (int j = 0; j < 30; ++j) {
            int g = t + j * 256;          // 0..7679
            int i = g / 960;              // 960 granules per i
            int r = g - i * 960;
            int w = r >> 5;
            int c = r & 31;
            f16x8 v = *(const f16x8*)(vg + (size_t)g * 8);
            *(f16x8*)&vlds[(i * 30 + w) * 258 + c * 8] = v;
        }
    }
    for (int j = t; j < 8 * 16 * 31; j += 256) logits[j] = 0.f;
    __syncthreads();

    const float bias_t = bias[t];
    const int iA = t / 30;               // phase A/C mapping (t<240)
    const int wA = t - iA * 30;

    float pre[30];
    float scale = 0.f;

    for (int it = 0; it < 3; ++it) {
        // ---- Phase A: route = softmax_o(logits); threads (i,w)
        if (t < 240) {
            float l[16], m = -1e30f;
            #pragma unroll
            for (int oo = 0; oo < 16; ++oo) {
                l[oo] = logits[(iA * 16 + oo) * 31 + wA];
                m = fmaxf(m, l[oo]);
            }
            float s = 0.f;
            #pragma unroll
            for (int oo = 0; oo < 16; ++oo) { l[oo] = __expf(l[oo] - m); s += l[oo]; }
            float inv = 1.f / s;
            #pragma unroll
            for (int oo = 0; oo < 16; ++oo)
                route16[(iA * 16 + oo) * 30 + wA] = (_Float16)(l[oo] * inv);
        }
        __syncthreads();

        // ---- Phase B: thread (o,a)=t: pre[w] = bias + sum_i route*votes
        #pragma unroll
        for (int w = 0; w < 30; ++w) pre[w] = bias_t;
        #pragma unroll
        for (int i = 0; i < 8; ++i) {
            const _Float16* vrow = &vlds[i * 30 * 258 + t];
            const _Float16* rrow = &route16[(i * 16 + o) * 30];
            #pragma unroll
            for (int w = 0; w < 30; ++w)
                pre[w] = fmaf((float)rrow[w], (float)vrow[w * 258], pre[w]);
        }
        float s2 = 0.f;
        #pragma unroll
        for (int w = 0; w < 30; ++w) s2 = fmaf(pre[w], pre[w], s2);
        scale = s2 / ((1.f + s2) * sqrtf(s2 + 1e-7f));

        if (it < 2) {
            #pragma unroll
            for (int w = 0; w < 30; ++w)
                act16[w * 258 + t] = (_Float16)(scale * pre[w]);
            __syncthreads();
            // ---- Phase C: thread (i,w): logits[i,o,w] += sum_a v*act
            if (t < 240) {
                const _Float16* vrow = &vlds[(iA * 30 + wA) * 258];
                const _Float16* arow = &act16[wA * 258];
                #pragma unroll
                for (int oo = 0; oo < 16; ++oo) {
                    float s = 0.f;
                    #pragma unroll
                    for (int k = 0; k < 8; ++k) {
                        f16x2 v2 = *(const f16x2*)&vrow[oo * 16 + 2 * k];
                        f16x2 a2 = *(const f16x2*)&arow[oo * 16 + 2 * k];
                        s = fmaf((float)v2[0], (float)a2[0], s);
                        s = fmaf((float)v2[1], (float)a2[1], s);
                    }
                    logits[(iA * 16 + oo) * 31 + wA] += s;
                }
            }
            __syncthreads();
        }
    }

    // ---- output: out[b,h,w,o,a] from registers, coalesced
    float* ob = out + (size_t)((b * 30 + h) * 30) * 256;
    #pragma unroll
    for (int w = 0; w < 30; ++w) ob[w * 256 + t] = scale * pre[w];
}

extern "C" void kernel_launch(void* const* d_in, const int* in_sizes, int n_in,
                              void* d_out, int out_size, void* d_ws, size_t ws_size,
                              hipStream_t stream)
{
    const float* x    = (const float*)d_in[0];  // [32,32,32,8,16]
    const float* Wt   = (const float*)d_in[1];  // [16,3,3,1,256] = [144][256]
    const float* bias = (const float*)d_in[2];  // [16,16,1,1]
    float* out = (float*)d_out;                 // [32,30,30,16,16]
    _Float16* votes = (_Float16*)d_ws;                     // 117,964,800 B
    _Float16* wt_h  = (_Float16*)((char*)d_ws + WT_OFF);   // [256][160] fp16

    prep_wt_kernel<<<dim3(144), 256, 0, stream>>>(Wt, wt_h);
    conv_mfma_kernel<<<dim3(32, 8, 15), 256, 0, stream>>>(x, wt_h, votes);
    routing_kernel<<<dim3(30, 32), 256, 0, stream>>>(votes, bias, out);
}